// Round 24
// baseline (1522.296 us; speedup 1.0000x reference)
//
#include <hip/hip_runtime.h>

#define T_STEPS 512
#define BATCH   128
#define DIN     256
#define DLAT    512

typedef __bf16 bf16x8 __attribute__((ext_vector_type(8)));
typedef float  f32x4  __attribute__((ext_vector_type(4)));
typedef int    i32x4  __attribute__((ext_vector_type(4)));
typedef unsigned long long u64;

__device__ __forceinline__ unsigned int f2bf2(float a, float b) {
  unsigned int ua = __float_as_uint(a);
  unsigned int ub = __float_as_uint(b);
  ua = (ua + 0x7FFFu + ((ua >> 16) & 1u)) >> 16;
  ub = (ub + 0x7FFFu + ((ub >> 16) & 1u)) >> 16;
  return ua | (ub << 16);
}

__device__ __forceinline__ uint4 pack8(float4 f0, float4 f1) {
  uint4 r;
  r.x = f2bf2(f0.x, f0.y);
  r.y = f2bf2(f0.z, f0.w);
  r.z = f2bf2(f1.x, f1.y);
  r.w = f2bf2(f1.z, f1.w);
  return r;
}

// ---------------- Kernel P: prepack Wh fp32 -> bf16 row-major in workspace ----------------
extern "C" __global__ __launch_bounds__(256) void pk_wh(
    const float* __restrict__ Wh, unsigned int* __restrict__ out) {
  int idx = blockIdx.x * 256 + threadIdx.x;   // 0..32767, 8 f32 each
  const float* src = Wh + (long)idx * 8;
  float4 f0 = *(const float4*)src;
  float4 f1 = *(const float4*)(src + 4);
  uint4 v = pack8(f0, f1);
  *(uint4*)(out + (long)idx * 4) = v;
}

// ---------------- Kernel A: Xi = X @ Wi^T + (bi + bh), written into d_out ----------------
extern "C" __global__ __launch_bounds__(256) void xi_gemm(
    const float* __restrict__ X, const float* __restrict__ Wi,
    const float* __restrict__ bi, const float* __restrict__ bh,
    float* __restrict__ XiOut) {
  extern __shared__ char smem[];
  char*  sX    = smem;                      // 65536 B: [128 rows][512 B] swizzled
  char*  sW    = smem + 65536;              // 65536 B
  float* sBias = (float*)(smem + 131072);   // 128 floats

  const int tid = threadIdx.x;
  const long m0 = (long)blockIdx.x * 128;   // over T*B = 65536
  const int  n0 = blockIdx.y * 128;         // over DLAT

  #pragma unroll
  for (int c = 0; c < 16; ++c) {
    int id = c * 256 + tid;                 // 0..4095
    int r  = id >> 5;                       // 0..127
    int kc = (id & 31) << 3;                // 0..248
    const float* sx = X + (m0 + r) * DIN + kc;
    float4 a0 = *(const float4*)sx;
    float4 a1 = *(const float4*)(sx + 4);
    int ax = ((r << 9) + (kc << 1)) ^ ((r & 7) << 4);
    *(uint4*)(sX + ax) = pack8(a0, a1);
    const float* sw = Wi + (n0 + r) * DIN + kc;
    float4 b0 = *(const float4*)sw;
    float4 b1 = *(const float4*)(sw + 4);
    *(uint4*)(sW + ax) = pack8(b0, b1);
  }
  if (tid < 128) sBias[tid] = bi[n0 + tid] + bh[n0 + tid];
  __syncthreads();

  const int w = tid >> 6, lane = tid & 63;
  const int wm = (w >> 1) * 64, wn = (w & 1) * 64;
  const int lm = lane & 15, lq = lane >> 4;

  f32x4 acc[4][4];
  #pragma unroll
  for (int nt = 0; nt < 4; ++nt) {
    float bv = sBias[wn + nt * 16 + lm];
    #pragma unroll
    for (int mt = 0; mt < 4; ++mt) acc[mt][nt] = f32x4{bv, bv, bv, bv};
  }

  #pragma unroll
  for (int k0 = 0; k0 < 8; ++k0) {
    int kb = (k0 << 6) + (lq << 4);
    bf16x8 af[4], bfr[4];
    #pragma unroll
    for (int mt = 0; mt < 4; ++mt) {
      int row = wm + mt * 16 + lm;
      int ax = ((row << 9) + kb) ^ ((row & 7) << 4);
      af[mt] = __builtin_bit_cast(bf16x8, *(uint4*)(sX + ax));
    }
    #pragma unroll
    for (int nt = 0; nt < 4; ++nt) {
      int row = wn + nt * 16 + lm;
      int ax = ((row << 9) + kb) ^ ((row & 7) << 4);
      bfr[nt] = __builtin_bit_cast(bf16x8, *(uint4*)(sW + ax));
    }
    #pragma unroll
    for (int mt = 0; mt < 4; ++mt)
      #pragma unroll
      for (int nt = 0; nt < 4; ++nt)
        acc[mt][nt] = __builtin_amdgcn_mfma_f32_16x16x32_bf16(af[mt], bfr[nt], acc[mt][nt], 0, 0, 0);
  }

  #pragma unroll
  for (int mt = 0; mt < 4; ++mt) {
    #pragma unroll
    for (int e = 0; e < 4; ++e) {
      long m = m0 + wm + mt * 16 + (lq << 2) + e;
      float* dst = XiOut + m * DLAT + n0 + wn + lm;
      #pragma unroll
      for (int nt = 0; nt < 4; ++nt)
        dst[nt * 16] = acc[mt][nt][e];
    }
  }
}

// ---------------- Kernel B: n-split x2 recurrence, L3-coherent exchange ----------------
// 16 blocks = 8 batch-groups x 2 n-HALVES; 512 threads; wave w owns TWO n-tiles
// (nt = p*256 + w*32, +16): wreg[2][16] = 128 quads, AGPR-resident (r13-r19 evidence:
// VGPR_Count 60-68 < wreg size => compiler places wreg in the AGPR half; unified budget
// 256 regs/wave at 2 waves/EU => 128 AGPR + ~70 arch VGPR fits).
// WHY x2: r19-r23 showed the residual step cost is the cross-block straggler wait --
// r19 polls 3 sibling flags (E[max of 3 skews]); halving fan-in to ONE sibling removes
// most of that variance. Everything else is the r19 skeleton verbatim (it beat all 5
// variants): publish -> own-wave vmcnt drain -> barrier #1 -> tid0 single-writer flag
// -> shadow window (own-slice into sH, HO store, xi prefetch) -> FUSED speculative
// poll (1 flag + 2 same-iteration data u64) -> commit -> barrier #2.
// Depth-2 parity audit (unchanged): X's t+2 slot overwrite <- X's t+1 barrier <- X's
// t+1 poll saw Y's flag[t+1] <- Y stored it after its t+1 barrier #1 <- after Y's t+1
// MFMA <- after Y's t barrier #2, whose drain completed Y's t-commit loads.
// flags[g][p][t] single-writer, zeroed per launch (graph-safe).
extern "C" __global__ __launch_bounds__(512, 2) void rnn_scan(
    const float* __restrict__ h0, const unsigned short* __restrict__ WhP,
    float* __restrict__ HO, u64* __restrict__ hx,
    unsigned int* __restrict__ flags) {
  __shared__ uint4 sH4[1024];   // 16 KB: [m=16][k=512] bf16, rows 1024 B, XOR-swizzled
  char* sH = (char*)sH4;

  const int tid = threadIdx.x;
  const int w = tid >> 6, lane = tid & 63;
  const int lm = lane & 15, lq = lane >> 4;
  const int g  = blockIdx.x & 7;      // batch group: rows [g*16, g*16+16)
  const int p  = blockIdx.x >> 3;     // n-half: cols [p*256, p*256+256)
  const int r0 = g << 4;
  const int nt = (p << 8) + (w << 5); // wave's first n-tile (second at +16)

  // Wh slices: lane holds Wh[nt + t0*16 + lm][kq*32 + lq*8 .. +7], 128 quads -> AGPR
  i32x4 wreg[2][16];
  #pragma unroll
  for (int t0 = 0; t0 < 2; ++t0) {
    const unsigned short* base = WhP + (nt + t0 * 16 + lm) * DLAT + (lq << 3);
    #pragma unroll
    for (int kq = 0; kq < 16; ++kq)
      wreg[t0][kq] = *(const i32x4*)(base + kq * 32);
  }
  #pragma unroll
  for (int t0 = 0; t0 < 2; ++t0)
    #pragma unroll
    for (int kq = 0; kq < 16; ++kq)
      asm("" : "+v"(wreg[t0][kq]));   // anti-remat pin (asm def)

  // initial h from h0: 16 rows x 64 chunks(16B) = 1024 -> 2 iters x 512 threads
  #pragma unroll
  for (int c = 0; c < 2; ++c) {
    int id = c * 512 + tid;
    int m = id >> 6, kc = (id & 63) << 3;
    const float* src = h0 + (r0 + m) * DLAT + kc;
    float4 f0 = *(const float4*)src;
    float4 f1 = *(const float4*)(src + 4);
    int ax = ((m << 10) + (kc << 1)) ^ ((m & 7) << 4);
    *(uint4*)(sH + ax) = pack8(f0, f1);
  }
  __syncthreads();

  const int mask  = (lm & 7) << 4;
  const int hbase = (lm << 10) + (lq << 4);
  const int ncol  = nt + (lq << 2);              // tile0 cols; tile1 at +16 (row m = lm)
  unsigned int* fgrp = flags + (g << 11);        // flags[g][p][t]: (p<<9)+t
  const int sp = p ^ 1;                          // the single sibling half
  const int rm = tid >> 5, rj = tid & 31;        // rebuild: row 0..15, chunk 0..31
  const int i1 = (rm << 7) + (sp << 6) + rj;     // sibling chunks rj and rj+32
  const int i2 = i1 + 32;

  // prefetch xi for t = 0 (Xi lives in HO, written by xi_gemm)
  float4 xi0, xi1;
  {
    const float* xr = HO + (long)(r0 + lm) * DLAT + ncol;
    xi0 = *(const float4*)xr;
    xi1 = *(const float4*)(xr + 16);
  }

  for (int t = 0; t < T_STEPS; ++t) {
    // z^T[n][m] = sum_k Wh[n][k] * h[m][k]; 4 independent chains (2 per tile)
    f32x4 a00 = f32x4{0.f, 0.f, 0.f, 0.f};
    f32x4 a01 = f32x4{0.f, 0.f, 0.f, 0.f};
    f32x4 a10 = f32x4{0.f, 0.f, 0.f, 0.f};
    f32x4 a11 = f32x4{0.f, 0.f, 0.f, 0.f};
    #pragma unroll
    for (int kq = 0; kq < 16; kq += 2) {
      bf16x8 hb0 = __builtin_bit_cast(bf16x8, *(uint4*)(sH + ((hbase + kq * 64) ^ mask)));
      bf16x8 hb1 = __builtin_bit_cast(bf16x8, *(uint4*)(sH + ((hbase + (kq + 1) * 64) ^ mask)));
      a00 = __builtin_amdgcn_mfma_f32_16x16x32_bf16(
          __builtin_bit_cast(bf16x8, wreg[0][kq]), hb0, a00, 0, 0, 0);
      a10 = __builtin_amdgcn_mfma_f32_16x16x32_bf16(
          __builtin_bit_cast(bf16x8, wreg[1][kq]), hb0, a10, 0, 0, 0);
      a01 = __builtin_amdgcn_mfma_f32_16x16x32_bf16(
          __builtin_bit_cast(bf16x8, wreg[0][kq + 1]), hb1, a01, 0, 0, 0);
      a11 = __builtin_amdgcn_mfma_f32_16x16x32_bf16(
          __builtin_bit_cast(bf16x8, wreg[1][kq + 1]), hb1, a11, 0, 0, 0);
    }

    // h = tanh(z + xi) for both tiles
    float hv0[4], hv1[4];
    #pragma unroll
    for (int e = 0; e < 4; ++e) {
      float z0 = (a00[e] + a01[e]) + ((float*)&xi0)[e];
      float z1 = (a10[e] + a11[e]) + ((float*)&xi1)[e];
      float e0 = __expf(2.0f * z0);
      float e1 = __expf(2.0f * z1);
      hv0[e] = 1.0f - 2.0f / (e0 + 1.0f);
      hv1[e] = 1.0f - 2.0f / (e1 + 1.0f);
    }

    u64 v0 = (u64)f2bf2(hv0[0], hv0[1]) | ((u64)f2bf2(hv0[2], hv0[3]) << 32);
    u64 v1 = (u64)f2bf2(hv1[0], hv1[1]) | ((u64)f2bf2(hv1[2], hv1[3]) << 32);

    if (t + 1 < T_STEPS) {
      u64* hxg = hx + ((long)(t & 1) << 14) + ((long)g << 11);  // parity 16384, group 2048 u64
      const int pubi = (lm << 7) + (ncol >> 2);                 // tile0; tile1 at +4

      // publish both tiles (2 x 8-B L3 writes); drain waits only on these
      __hip_atomic_store(&hxg[pubi],     v0, __ATOMIC_RELAXED, __HIP_MEMORY_SCOPE_AGENT);
      __hip_atomic_store(&hxg[pubi + 4], v1, __ATOMIC_RELAXED, __HIP_MEMORY_SCOPE_AGENT);
      asm volatile("s_waitcnt vmcnt(0)" ::: "memory");
      __syncthreads();   // barrier #1: all MFMA reads done + ALL publishes at L3

      // single-writer flag: tid0 STOREs 1 (no RMW)
      if (tid == 0)
        __hip_atomic_store(&fgrp[(p << 9) + t], 1u,
                           __ATOMIC_RELAXED, __HIP_MEMORY_SCOPE_AGENT);

      // overlap window: own slices into sH, HO stores, next-xi prefetch
      {
        int ax0 = ((lm << 10) + (ncol << 1)) ^ mask;
        int ax1 = ((lm << 10) + ((ncol + 16) << 1)) ^ mask;
        *(u64*)(sH + ax0) = v0;
        *(u64*)(sH + ax1) = v1;
        float* orow = HO + ((long)t * BATCH + r0 + lm) * DLAT + ncol;
        float4 o0; o0.x = hv0[0]; o0.y = hv0[1]; o0.z = hv0[2]; o0.w = hv0[3];
        float4 o1; o1.x = hv1[0]; o1.y = hv1[1]; o1.z = hv1[2]; o1.w = hv1[3];
        *(float4*)orow = o0;
        *(float4*)(orow + 16) = o1;
        const float* xr = HO + ((long)(t + 1) * BATCH + r0 + lm) * DLAT + ncol;
        xi0 = *(const float4*)xr;
        xi1 = *(const float4*)(xr + 16);
      }

      // FUSED speculative poll + rebuild: lane 0 watches the single sibling flag;
      // data sampled in the iteration where the flag is set is provably post-publish.
      u64 d1, d2;
      for (;;) {
        d1 = __hip_atomic_load(&hxg[i1], __ATOMIC_RELAXED, __HIP_MEMORY_SCOPE_AGENT);
        d2 = __hip_atomic_load(&hxg[i2], __ATOMIC_RELAXED, __HIP_MEMORY_SCOPE_AGENT);
        unsigned int fv = (lane == 0)
            ? __hip_atomic_load(&fgrp[(sp << 9) + t], __ATOMIC_RELAXED, __HIP_MEMORY_SCOPE_AGENT)
            : 1u;
        if (!__any(fv == 0u)) break;
      }
      asm volatile("" ::: "memory");

      // commit the sibling half -> sH
      {
        int c1 = (sp << 6) + rj;
        int c2 = c1 + 32;
        int ax1 = ((rm << 10) + (c1 << 3)) ^ ((rm & 7) << 4);
        int ax2 = ((rm << 10) + (c2 << 3)) ^ ((rm & 7) << 4);
        *(u64*)(sH + ax1) = d1;
        *(u64*)(sH + ax2) = d2;
      }

      __syncthreads();   // barrier #2: sH fully rebuilt before next step's MFMA
    } else {
      float* orow = HO + ((long)t * BATCH + r0 + lm) * DLAT + ncol;
      float4 o0; o0.x = hv0[0]; o0.y = hv0[1]; o0.z = hv0[2]; o0.w = hv0[3];
      float4 o1; o1.x = hv1[0]; o1.y = hv1[1]; o1.z = hv1[2]; o1.w = hv1[3];
      *(float4*)orow = o0;
      *(float4*)(orow + 16) = o1;
    }
  }
}

extern "C" void kernel_launch(void* const* d_in, const int* in_sizes, int n_in,
                              void* d_out, int out_size, void* d_ws, size_t ws_size,
                              hipStream_t stream) {
  const float* X  = (const float*)d_in[0];
  const float* h0 = (const float*)d_in[1];
  const float* Wi = (const float*)d_in[2];
  const float* bi = (const float*)d_in[3];
  const float* Wh = (const float*)d_in[4];
  const float* bh = (const float*)d_in[5];
  float* out = (float*)d_out;

  // ws: [0,512K) WhP bf16; [512K,768K) hx (2 parities x 8 groups x 16 KB);
  //     [768K,832K) flags u32[8][2][512] (single-writer, zeroed per launch)
  unsigned int* whp   = (unsigned int*)d_ws;
  u64*          hx    = (u64*)((char*)d_ws + 524288);
  unsigned int* flags = (unsigned int*)((char*)d_ws + 786432);

  hipMemsetAsync(flags, 0, 65536, stream);   // re-zeroed on every (graph) replay

  hipFuncSetAttribute((const void*)xi_gemm, hipFuncAttributeMaxDynamicSharedMemorySize, 131584);

  pk_wh<<<128, 256, 0, stream>>>(Wh, whp);
  xi_gemm<<<dim3(512, 4), 256, 131584, stream>>>(X, Wi, bi, bh, out);
  rnn_scan<<<16, 512, 0, stream>>>(h0, (const unsigned short*)whp, out, hx, flags);
}

// Round 25
// 1161.598 us; speedup vs baseline: 1.3105x; 1.3105x over previous
//
#include <hip/hip_runtime.h>

#define T_STEPS 512
#define BATCH   128
#define DIN     256
#define DLAT    512

typedef __bf16 bf16x8 __attribute__((ext_vector_type(8)));
typedef float  f32x4  __attribute__((ext_vector_type(4)));
typedef int    i32x4  __attribute__((ext_vector_type(4)));
typedef unsigned long long u64;

__device__ __forceinline__ unsigned int f2bf2(float a, float b) {
  unsigned int ua = __float_as_uint(a);
  unsigned int ub = __float_as_uint(b);
  ua = (ua + 0x7FFFu + ((ua >> 16) & 1u)) >> 16;
  ub = (ub + 0x7FFFu + ((ub >> 16) & 1u)) >> 16;
  return ua | (ub << 16);
}

__device__ __forceinline__ uint4 pack8(float4 f0, float4 f1) {
  uint4 r;
  r.x = f2bf2(f0.x, f0.y);
  r.y = f2bf2(f0.z, f0.w);
  r.z = f2bf2(f1.x, f1.y);
  r.w = f2bf2(f1.z, f1.w);
  return r;
}

// ---------------- Kernel P: prepack Wh fp32 -> bf16 row-major in workspace ----------------
extern "C" __global__ __launch_bounds__(256) void pk_wh(
    const float* __restrict__ Wh, unsigned int* __restrict__ out) {
  int idx = blockIdx.x * 256 + threadIdx.x;   // 0..32767, 8 f32 each
  const float* src = Wh + (long)idx * 8;
  float4 f0 = *(const float4*)src;
  float4 f1 = *(const float4*)(src + 4);
  uint4 v = pack8(f0, f1);
  *(uint4*)(out + (long)idx * 4) = v;
}

// ---------------- Kernel A: Xi = X @ Wi^T + (bi + bh), written into d_out ----------------
extern "C" __global__ __launch_bounds__(256) void xi_gemm(
    const float* __restrict__ X, const float* __restrict__ Wi,
    const float* __restrict__ bi, const float* __restrict__ bh,
    float* __restrict__ XiOut) {
  extern __shared__ char smem[];
  char*  sX    = smem;                      // 65536 B: [128 rows][512 B] swizzled
  char*  sW    = smem + 65536;              // 65536 B
  float* sBias = (float*)(smem + 131072);   // 128 floats

  const int tid = threadIdx.x;
  const long m0 = (long)blockIdx.x * 128;   // over T*B = 65536
  const int  n0 = blockIdx.y * 128;         // over DLAT

  #pragma unroll
  for (int c = 0; c < 16; ++c) {
    int id = c * 256 + tid;                 // 0..4095
    int r  = id >> 5;                       // 0..127
    int kc = (id & 31) << 3;                // 0..248
    const float* sx = X + (m0 + r) * DIN + kc;
    float4 a0 = *(const float4*)sx;
    float4 a1 = *(const float4*)(sx + 4);
    int ax = ((r << 9) + (kc << 1)) ^ ((r & 7) << 4);
    *(uint4*)(sX + ax) = pack8(a0, a1);
    const float* sw = Wi + (n0 + r) * DIN + kc;
    float4 b0 = *(const float4*)sw;
    float4 b1 = *(const float4*)(sw + 4);
    *(uint4*)(sW + ax) = pack8(b0, b1);
  }
  if (tid < 128) sBias[tid] = bi[n0 + tid] + bh[n0 + tid];
  __syncthreads();

  const int w = tid >> 6, lane = tid & 63;
  const int wm = (w >> 1) * 64, wn = (w & 1) * 64;
  const int lm = lane & 15, lq = lane >> 4;

  f32x4 acc[4][4];
  #pragma unroll
  for (int nt = 0; nt < 4; ++nt) {
    float bv = sBias[wn + nt * 16 + lm];
    #pragma unroll
    for (int mt = 0; mt < 4; ++mt) acc[mt][nt] = f32x4{bv, bv, bv, bv};
  }

  #pragma unroll
  for (int k0 = 0; k0 < 8; ++k0) {
    int kb = (k0 << 6) + (lq << 4);
    bf16x8 af[4], bfr[4];
    #pragma unroll
    for (int mt = 0; mt < 4; ++mt) {
      int row = wm + mt * 16 + lm;
      int ax = ((row << 9) + kb) ^ ((row & 7) << 4);
      af[mt] = __builtin_bit_cast(bf16x8, *(uint4*)(sX + ax));
    }
    #pragma unroll
    for (int nt = 0; nt < 4; ++nt) {
      int row = wn + nt * 16 + lm;
      int ax = ((row << 9) + kb) ^ ((row & 7) << 4);
      bfr[nt] = __builtin_bit_cast(bf16x8, *(uint4*)(sW + ax));
    }
    #pragma unroll
    for (int mt = 0; mt < 4; ++mt)
      #pragma unroll
      for (int nt = 0; nt < 4; ++nt)
        acc[mt][nt] = __builtin_amdgcn_mfma_f32_16x16x32_bf16(af[mt], bfr[nt], acc[mt][nt], 0, 0, 0);
  }

  #pragma unroll
  for (int mt = 0; mt < 4; ++mt) {
    #pragma unroll
    for (int e = 0; e < 4; ++e) {
      long m = m0 + wm + mt * 16 + (lq << 2) + e;
      float* dst = XiOut + m * DLAT + n0 + wn + lm;
      #pragma unroll
      for (int nt = 0; nt < 4; ++nt)
        dst[nt * 16] = acc[mt][nt][e];
    }
  }
}

// ---------------- Kernel B: n-split x4 recurrence, L3-coherent exchange (r19 final) ------
// 32 blocks = 8 batch-groups x 4 n-quarters; 512 threads; wave w owns ONE n-tile
// (nt = q*128 + w*16), Wh slice = wreg[16] = 64 regs (AGPR-resident via AV operand
// class). LDS = 16 KB sH only (r18: every wave consumes ALL of h -> LDS broadcast
// dedup is essential).
// Sync skeleton -- the measured optimum of 6 topology variants (r16-r24):
//   publish h-slice (8-B L3 relaxed-atomic write) -> own vmcnt(0) drain -> barrier #1
//   -> tid0 single-writer flag STORE -> shadow window (own-slice into sH, HO store,
//   xi prefetch) -> FUSED speculative poll (3 sibling flags + same-iteration data
//   sampling; commit the data sampled in the iteration where all flags read 1) ->
//   commit -> barrier #2.
// Fused-poll safety: writer stores flag only after its data's vmcnt(0) ack (data at L3
// at T1, flag visible at T2 >= T1 + ~transit); reader's same-iteration data/flag
// samples skew by tens of cycles << transit, so flag==1 implies the data sample is
// post-T1. Partial values appear only in DISCARDED iterations.
// Depth-2 parity audit: X's t+2 slot overwrite <- X's t+1 barrier <- X's t+1 poll saw
// Y's flag[t+1] <- Y stored it after its t+1 barrier #1 <- after Y's t+1 MFMA <- after
// Y's t barrier #2, whose drain completed Y's t-commit loads.
// flags[g][q][t] single-writer, zeroed per launch (graph-safe).
// Structural floor note: per sequential step the group state (1 KB) must cross CU
// boundaries -> >= 2 L3 coherence RTTs/step (~1.4 us) + compute (~0.35 us) +
// barriers. Measured 2.11 us/step. HBM 3.5% / MFMA ~1% -- latency-bound, not
// bandwidth/compute-bound.
extern "C" __global__ __launch_bounds__(512, 2) void rnn_scan(
    const float* __restrict__ h0, const unsigned short* __restrict__ WhP,
    float* __restrict__ HO, u64* __restrict__ hx,
    unsigned int* __restrict__ flags) {
  __shared__ uint4 sH4[1024];   // 16 KB: [m=16][k=512] bf16, rows 1024 B, XOR-swizzled
  char* sH = (char*)sH4;

  const int tid = threadIdx.x;
  const int w = tid >> 6, lane = tid & 63;
  const int lm = lane & 15, lq = lane >> 4;
  const int g  = blockIdx.x & 7;      // batch group: rows [g*16, g*16+16)
  const int q  = blockIdx.x >> 3;     // n-quarter:  cols [q*128, q*128+128)
  const int r0 = g << 4;
  const int nt = (q << 7) + (w << 4); // wave's n-tile

  // Wh slice: lane holds Wh[nt+lm][kq*32 + lq*8 .. +7], kq = 0..15 (64 regs)
  i32x4 wreg[16];
  {
    const unsigned short* base = WhP + (nt + lm) * DLAT + (lq << 3);
    #pragma unroll
    for (int kq = 0; kq < 16; ++kq)
      wreg[kq] = *(const i32x4*)(base + kq * 32);
    #pragma unroll
    for (int kq = 0; kq < 16; ++kq)
      asm("" : "+v"(wreg[kq]));   // anti-remat pin (asm def)
  }

  // initial h from h0: 16 rows x 64 chunks(16B) = 1024 -> 2 iters x 512 threads
  #pragma unroll
  for (int c = 0; c < 2; ++c) {
    int id = c * 512 + tid;
    int m = id >> 6, kc = (id & 63) << 3;
    const float* src = h0 + (r0 + m) * DLAT + kc;
    float4 f0 = *(const float4*)src;
    float4 f1 = *(const float4*)(src + 4);
    int ax = ((m << 10) + (kc << 1)) ^ ((m & 7) << 4);
    *(uint4*)(sH + ax) = pack8(f0, f1);
  }
  __syncthreads();

  const int mask  = (lm & 7) << 4;
  const int hbase = (lm << 10) + (lq << 4);
  const int ncol  = nt + (lq << 2);              // thread's 4 consecutive n (row m = lm)
  unsigned int* fgrp = flags + (g << 11);        // flags[g][q][t]: (q<<9)+t
  const int sq = (q + 1 + lane) & 3;             // lanes 0..2 -> the 3 siblings
  const int rm = tid >> 5, rj = tid & 31;        // rebuild: row 0..15, chunk 0..31
  const int q1 = (q + 1) & 3, q2 = (q + 2) & 3, q3 = (q + 3) & 3;
  const int i1 = (rm << 7) + (q1 << 5) + rj;
  const int i2 = (rm << 7) + (q2 << 5) + rj;
  const int i3 = (rm << 7) + (q3 << 5) + rj;

  // prefetch xi for t = 0 (Xi lives in HO, written by xi_gemm)
  float4 xi = *(const float4*)(HO + (long)(r0 + lm) * DLAT + ncol);

  for (int t = 0; t < T_STEPS; ++t) {
    // z^T[n][m] = sum_k Wh[n][k] * h[m][k]; 4 chains (depth 4) for MFMA-latency ILP
    f32x4 a0 = f32x4{0.f, 0.f, 0.f, 0.f};
    f32x4 a1 = f32x4{0.f, 0.f, 0.f, 0.f};
    f32x4 a2 = f32x4{0.f, 0.f, 0.f, 0.f};
    f32x4 a3 = f32x4{0.f, 0.f, 0.f, 0.f};
    #pragma unroll
    for (int kq = 0; kq < 16; kq += 4) {
      bf16x8 hb0 = __builtin_bit_cast(bf16x8, *(uint4*)(sH + ((hbase + kq * 64) ^ mask)));
      bf16x8 hb1 = __builtin_bit_cast(bf16x8, *(uint4*)(sH + ((hbase + (kq + 1) * 64) ^ mask)));
      bf16x8 hb2 = __builtin_bit_cast(bf16x8, *(uint4*)(sH + ((hbase + (kq + 2) * 64) ^ mask)));
      bf16x8 hb3 = __builtin_bit_cast(bf16x8, *(uint4*)(sH + ((hbase + (kq + 3) * 64) ^ mask)));
      a0 = __builtin_amdgcn_mfma_f32_16x16x32_bf16(
          __builtin_bit_cast(bf16x8, wreg[kq]), hb0, a0, 0, 0, 0);
      a1 = __builtin_amdgcn_mfma_f32_16x16x32_bf16(
          __builtin_bit_cast(bf16x8, wreg[kq + 1]), hb1, a1, 0, 0, 0);
      a2 = __builtin_amdgcn_mfma_f32_16x16x32_bf16(
          __builtin_bit_cast(bf16x8, wreg[kq + 2]), hb2, a2, 0, 0, 0);
      a3 = __builtin_amdgcn_mfma_f32_16x16x32_bf16(
          __builtin_bit_cast(bf16x8, wreg[kq + 3]), hb3, a3, 0, 0, 0);
    }

    // h = tanh(z + xi)
    float hv[4];
    #pragma unroll
    for (int e = 0; e < 4; ++e) {
      float z = (a0[e] + a1[e]) + (a2[e] + a3[e]) + ((float*)&xi)[e];
      float ex = __expf(2.0f * z);
      hv[e] = 1.0f - 2.0f / (ex + 1.0f);
    }

    if (t + 1 < T_STEPS) {
      u64* hxg = hx + ((long)(t & 1) << 14) + ((long)g << 11);  // parity 16384, group 2048 u64
      u64 v = ((u64)f2bf2(hv[2], hv[3]) << 32) | (u64)f2bf2(hv[0], hv[1]);

      // publish for siblings (8-B L3 write); drain waits only on this
      __hip_atomic_store(&hxg[(lm << 7) + (ncol >> 2)], v,
                         __ATOMIC_RELAXED, __HIP_MEMORY_SCOPE_AGENT);
      asm volatile("s_waitcnt vmcnt(0)" ::: "memory");
      __syncthreads();   // all MFMA reads done + ALL publishes at L3

      // single-writer flag: tid0 STOREs 1 (no RMW)
      if (tid == 0)
        __hip_atomic_store(&fgrp[(q << 9) + t], 1u,
                           __ATOMIC_RELAXED, __HIP_MEMORY_SCOPE_AGENT);

      // overlap window: own-slice into sH, HO store, next-xi prefetch
      {
        int ax = ((lm << 10) + (ncol << 1)) ^ mask;
        *(u64*)(sH + ax) = v;   // same bit pattern (2x u32 of 2x bf16)
        float4 o; o.x = hv[0]; o.y = hv[1]; o.z = hv[2]; o.w = hv[3];
        *(float4*)(HO + ((long)t * BATCH + r0 + lm) * DLAT + ncol) = o;
        xi = *(const float4*)(HO + ((long)(t + 1) * BATCH + r0 + lm) * DLAT + ncol);
      }

      // FUSED speculative poll + rebuild: data sampled in the same iteration where
      // all 3 sibling flags read 1 is provably post-publish (see header comment).
      u64 d1, d2, d3;
      for (;;) {
        d1 = __hip_atomic_load(&hxg[i1], __ATOMIC_RELAXED, __HIP_MEMORY_SCOPE_AGENT);
        d2 = __hip_atomic_load(&hxg[i2], __ATOMIC_RELAXED, __HIP_MEMORY_SCOPE_AGENT);
        d3 = __hip_atomic_load(&hxg[i3], __ATOMIC_RELAXED, __HIP_MEMORY_SCOPE_AGENT);
        unsigned int fv = (lane < 3)
            ? __hip_atomic_load(&fgrp[(sq << 9) + t], __ATOMIC_RELAXED, __HIP_MEMORY_SCOPE_AGENT)
            : 1u;
        if (!__any(fv == 0u)) break;
      }
      asm volatile("" ::: "memory");

      // commit the 3 sibling quarters to sH
      {
        int ax1 = ((rm << 10) + (((q1 << 5) + rj) << 3)) ^ ((rm & 7) << 4);
        int ax2 = ((rm << 10) + (((q2 << 5) + rj) << 3)) ^ ((rm & 7) << 4);
        int ax3 = ((rm << 10) + (((q3 << 5) + rj) << 3)) ^ ((rm & 7) << 4);
        *(u64*)(sH + ax1) = d1;
        *(u64*)(sH + ax2) = d2;
        *(u64*)(sH + ax3) = d3;
      }

      __syncthreads();   // barrier #2: sH fully rebuilt before next step's MFMA reads
    } else {
      float4 o; o.x = hv[0]; o.y = hv[1]; o.z = hv[2]; o.w = hv[3];
      *(float4*)(HO + ((long)t * BATCH + r0 + lm) * DLAT + ncol) = o;
    }
  }
}

extern "C" void kernel_launch(void* const* d_in, const int* in_sizes, int n_in,
                              void* d_out, int out_size, void* d_ws, size_t ws_size,
                              hipStream_t stream) {
  const float* X  = (const float*)d_in[0];
  const float* h0 = (const float*)d_in[1];
  const float* Wi = (const float*)d_in[2];
  const float* bi = (const float*)d_in[3];
  const float* Wh = (const float*)d_in[4];
  const float* bh = (const float*)d_in[5];
  float* out = (float*)d_out;

  // ws: [0,512K) WhP bf16; [512K,768K) hx (2 parities x 8 groups x 16 KB);
  //     [768K,832K) flags u32[8][4][512] = 64 KB (single-writer, zeroed per launch)
  unsigned int* whp   = (unsigned int*)d_ws;
  u64*          hx    = (u64*)((char*)d_ws + 524288);
  unsigned int* flags = (unsigned int*)((char*)d_ws + 786432);

  hipMemsetAsync(flags, 0, 65536, stream);   // re-zeroed on every (graph) replay

  hipFuncSetAttribute((const void*)xi_gemm, hipFuncAttributeMaxDynamicSharedMemorySize, 131584);

  pk_wh<<<128, 256, 0, stream>>>(Wh, whp);
  xi_gemm<<<dim3(512, 4), 256, 131584, stream>>>(X, Wi, bi, bh, out);
  rnn_scan<<<32, 512, 0, stream>>>(h0, (const unsigned short*)whp, out, hx, flags);
}